// Round 14
// baseline (209.105 us; speedup 1.0000x reference)
//
#include <hip/hip_runtime.h>
#include <hip/hip_bf16.h>

typedef float f32x4 __attribute__((ext_vector_type(4)));
typedef short s16x8 __attribute__((ext_vector_type(8)));
typedef short s16x4 __attribute__((ext_vector_type(4)));

#define NB 4
#define NT 2048
#define NH 16
#define DK 64
#define DM 1024
#define MTOT (NB * NT)   // 8192
#define NTOT (3 * DM)    // 3072

// log2(e) / sqrt(64)
#define QSCALE 0.18033688011112042f

__device__ __forceinline__ unsigned short f2bf(float f) {
  union { float f; unsigned u; } v; v.f = f;
  unsigned r = v.u + 0x7fff + ((v.u >> 16) & 1);
  return (unsigned short)(r >> 16);
}

__device__ __forceinline__ unsigned cvt_pk_bf16(float a, float b) {
  unsigned r;
  asm("v_cvt_pk_bf16_f32 %0, %1, %2" : "=v"(r) : "v"(a), "v"(b));
  return r;
}

// 16x16x16 bf16 MFMA (legacy K=16 shape; A/B = 4 bf16/lane at keys lh*4..+3,
// which matches the 16x16 C/D layout exactly -> no P redistribution needed)
__device__ __forceinline__ f32x4 mfma_16x16x16_bf16(s16x4 a, s16x4 b, f32x4 c) {
#if __has_builtin(__builtin_amdgcn_mfma_f32_16x16x16_bf16)
  return __builtin_amdgcn_mfma_f32_16x16x16_bf16(a, b, c, 0, 0, 0);
#elif __has_builtin(__builtin_amdgcn_mfma_f32_16x16x16bf16_1k)
  return __builtin_amdgcn_mfma_f32_16x16x16bf16_1k(a, b, c, 0, 0, 0);
#else
  f32x4 d;
  asm("v_mfma_f32_16x16x16_bf16 %0, %1, %2, %3"
      : "=v"(d) : "v"(a), "v"(b), "v"(c));
  return d;
#endif
}

__device__ __forceinline__ void async_copy16(void* lds, const void* g) {
  __builtin_amdgcn_global_load_lds(
      (const __attribute__((address_space(1))) unsigned int*)g,
      (__attribute__((address_space(3))) unsigned int*)lds, 16, 0, 0);
}

// ---------------- x -> bf16 ----------------
__global__ void cvt_x_kernel(const float* __restrict__ x,
                             unsigned short* __restrict__ xb) {
  int i = (blockIdx.x * 256 + threadIdx.x) * 4;
  float4 v = *reinterpret_cast<const float4*>(x + i);
  ushort4 o;
  o.x = f2bf(v.x); o.y = f2bf(v.y); o.z = f2bf(v.z); o.w = f2bf(v.w);
  *reinterpret_cast<ushort4*>(xb + i) = o;
}

// ---------------- W (1024,3072) f32 -> WT (3072,1024) bf16 ----------------
__global__ void transpose_w_kernel(const float* __restrict__ W,
                                   unsigned short* __restrict__ WT) {
  __shared__ float tile[64][65];
  const int n0 = blockIdx.x * 64;   // over 3072
  const int k0 = blockIdx.y * 64;   // over 1024
  const int t = threadIdx.x;        // 256
  const int col = t & 63;
  const int rw = t >> 6;
#pragma unroll
  for (int r = 0; r < 16; r++) {
    int row = r * 4 + rw;           // k offset
    tile[row][col] = W[(size_t)(k0 + row) * NTOT + n0 + col];
  }
  __syncthreads();
#pragma unroll
  for (int r = 0; r < 16; r++) {
    int row = r * 4 + rw;           // n offset
    WT[(size_t)(n0 + row) * DM + k0 + col] = f2bf(tile[col][row]);
  }
}

// ---------------- QKV GEMM (2-phase pipelined): C = Xb @ W + b ---------------
__global__ __launch_bounds__(256) void qkv_gemm_kernel(
    const unsigned short* __restrict__ A, const unsigned short* __restrict__ BT,
    const float* __restrict__ bias, unsigned short* __restrict__ Q,
    unsigned short* __restrict__ Kd, unsigned short* __restrict__ VT) {
  __shared__ unsigned short As[2][128 * 32];
  __shared__ unsigned short Bs[2][128 * 32];
  const int tid = threadIdx.x;
  const int lane = tid & 63;
  const int wave = tid >> 6;
  const int wr = wave >> 1, wc = wave & 1;
  const int l15 = lane & 15, lh = lane >> 4;

  const int nTilesN = NTOT / 128;  // 24
  const int tm = (blockIdx.x / nTilesN) * 128;
  const int tn = (blockIdx.x % nTilesN) * 128;

  const int srow = (tid >> 2), scol = (tid & 3) << 3;
  const int srow2 = ((256 + tid) >> 2), scol2 = ((256 + tid) & 3) << 3;

  f32x4 acc[4][4] = {};

  async_copy16(&As[0][(wave * 64) * 8], &A[(size_t)(tm + srow) * DM + scol]);
  async_copy16(&Bs[0][(wave * 64) * 8], &BT[(size_t)(tn + srow) * DM + scol]);
  async_copy16(&As[0][(256 + wave * 64) * 8], &A[(size_t)(tm + srow2) * DM + scol2]);
  async_copy16(&Bs[0][(256 + wave * 64) * 8], &BT[(size_t)(tn + srow2) * DM + scol2]);
  __syncthreads();

  int cur = 0;
  for (int k0 = 0; k0 < DM; k0 += 32) {
    if (k0 + 32 < DM) {
      const int nb = cur ^ 1, kn = k0 + 32;
      async_copy16(&As[nb][(wave * 64) * 8], &A[(size_t)(tm + srow) * DM + kn + scol]);
      async_copy16(&Bs[nb][(wave * 64) * 8], &BT[(size_t)(tn + srow) * DM + kn + scol]);
      async_copy16(&As[nb][(256 + wave * 64) * 8], &A[(size_t)(tm + srow2) * DM + kn + scol2]);
      async_copy16(&Bs[nb][(256 + wave * 64) * 8], &BT[(size_t)(tn + srow2) * DM + kn + scol2]);
    }
    s16x8 af[4], bf[4];
#pragma unroll
    for (int mi = 0; mi < 4; mi++)
      af[mi] = *(const s16x8*)&As[cur][(wr * 64 + mi * 16 + l15) * 32 + lh * 8];
#pragma unroll
    for (int ni = 0; ni < 4; ni++)
      bf[ni] = *(const s16x8*)&Bs[cur][(wc * 64 + ni * 16 + l15) * 32 + lh * 8];
    __builtin_amdgcn_s_setprio(1);
#pragma unroll
    for (int mi = 0; mi < 4; mi++)
#pragma unroll
      for (int ni = 0; ni < 4; ni++)
        acc[mi][ni] = __builtin_amdgcn_mfma_f32_16x16x32_bf16(
            af[mi], bf[ni], acc[mi][ni], 0, 0, 0);
    __builtin_amdgcn_s_setprio(0);
    __syncthreads();
    cur ^= 1;
  }

  // epilogue: bias + scatter
  const int part = tn >> 10;  // 0=Q 1=K 2=V (uniform per block)
#pragma unroll
  for (int ni = 0; ni < 4; ni++) {
    const int n = tn + wc * 64 + ni * 16 + l15;
    const float bv = bias[n];
    const int n1 = n & 1023;
    const int h = n1 >> 6, d = n1 & 63;
#pragma unroll
    for (int mi = 0; mi < 4; mi++) {
#pragma unroll
      for (int r = 0; r < 4; r++) {
        const int m = tm + wr * 64 + mi * 16 + lh * 4 + r;
        const int b = m >> 11, t = m & 2047;
        float v = acc[mi][ni][r] + bv;
        if (part == 0) {
          v *= QSCALE;
          Q[((size_t)(b * NH + h) * NT + t) * DK + d] = f2bf(v);
        } else if (part == 1) {
          Kd[((size_t)(b * NH + h) * NT + t) * DK + d] = f2bf(v);
        } else {
          VT[((size_t)(b * NH + h) * DK + d) * NT + t] = f2bf(v);
        }
      }
    }
  }
}

// ---------------- Flash attention v11 (P stays in registers) -----------------
// r13 structure (8-wave/512-thread blocks, shift-free softmax, K/V dbuf, one
// barrier/tile, XCD swizzle, setprio) with PV recast as 4x 16x16x16 MFMA per
// (mi,nd): the K=16 A-fragment (4 bf16 at keys lh*4..+3) EXACTLY matches the
// QK^T C/D layout, so the cvt_pk pairs feed PV directly from registers.
// Removes the whole Ps LDS round-trip (12 DS ops + mid-chain LDS latency +
// 16KB LDS + swizzle math). V B-frags become 16 b64 reads (same bytes).
// Q,K: (BH,T,64) bf16 (Q pre-scaled); VT: (BH,64,T) bf16; out fp32 (B,T,H,64).
// K/V swizzle: 16B chunk c of row at c^(row&7) (pre-swizzled global source,
// linear LDS dest); reads apply the same XOR.
__global__ __launch_bounds__(512) void attn_kernel(
    const unsigned short* __restrict__ Q, const unsigned short* __restrict__ K,
    const unsigned short* __restrict__ VT, float* __restrict__ out) {
  __shared__ unsigned short Ks[2][64 * 64];   // [buf][key][d]  2x8KB
  __shared__ unsigned short Vs[2][64 * 64];   // [buf][d][key]  2x8KB

  const int tid = threadIdx.x, lane = tid & 63, wave = tid >> 6;
  const int l15 = lane & 15, lh = lane >> 4;
  // XCD swizzle: 512 blocks, 8 XCDs -> XCD x gets orig ids [x*64, x*64+64)
  const int orig = ((blockIdx.x & 7) << 6) + (blockIdx.x >> 3);
  const int bh = orig >> 3;         // 64 (b,h) pairs
  const int qt = orig & 7;          // 8 q-tiles of 256 rows
  const size_t base = (size_t)bh * NT * DK;
  const int qrow0 = qt * 256 + wave * 32;

  // staging geometry: 512 threads cover one 64x64 bf16 tile (1 chunk each)
  const int srow = tid >> 3, schunk = tid & 7;
  const int ssw = ((schunk ^ (srow & 7)) << 3);

  // Q fragments (MFMA B operand): Q[query=l15][d=lh*8..]
  s16x8 qf[2][2];
#pragma unroll
  for (int mi = 0; mi < 2; mi++)
#pragma unroll
    for (int kk = 0; kk < 2; kk++)
      qf[mi][kk] = *(const s16x8*)&Q[base + (size_t)(qrow0 + mi * 16 + l15) * DK +
                                     kk * 32 + lh * 8];

  float msum[2] = {0.0f, 0.0f};
  f32x4 acc_o[2][4] = {};

  // prologue: stage K[0], V[0] into buf 0
  async_copy16(&Ks[0][(wave * 64) * 8], &K[base + (size_t)srow * DK + ssw]);
  async_copy16(&Vs[0][(wave * 64) * 8], &VT[base + (size_t)srow * NT + ssw]);
  __syncthreads();

  int cur = 0;
  for (int j = 0; j < NT; j += 64) {
    // prefetch NEXT tile's K and V into the ^1 buffers
    if (j + 64 < NT) {
      async_copy16(&Ks[cur ^ 1][(wave * 64) * 8],
                   &K[base + (size_t)(j + 64 + srow) * DK + ssw]);
      async_copy16(&Vs[cur ^ 1][(wave * 64) * 8],
                   &VT[base + (size_t)srow * NT + j + 64 + ssw]);
    }

    // S^T = K @ Q^T : st[ki][mi] rows=keys(ki*16+lh*4+r), cols=queries(mi*16+l15)
    f32x4 st[4][2] = {};
    __builtin_amdgcn_s_setprio(1);
#pragma unroll
    for (int ki = 0; ki < 4; ki++) {
      const int row = ki * 16 + l15;
      const unsigned short* kr = &Ks[cur][row * 64];
      s16x8 kf0 = *(const s16x8*)&kr[((lh ^ (row & 7)) << 3)];
      s16x8 kf1 = *(const s16x8*)&kr[(((4 + lh) ^ (row & 7)) << 3)];
#pragma unroll
      for (int mi = 0; mi < 2; mi++) {
        st[ki][mi] = __builtin_amdgcn_mfma_f32_16x16x32_bf16(kf0, qf[mi][0], st[ki][mi], 0, 0, 0);
        st[ki][mi] = __builtin_amdgcn_mfma_f32_16x16x32_bf16(kf1, qf[mi][1], st[ki][mi], 0, 0, 0);
      }
    }
    __builtin_amdgcn_s_setprio(0);

    // shift-free softmax: p = exp2(s); per-lane partial sums; pack bf16 pairs.
    // pa[mi][ki] = P[query=mi*16+l15][keys ki*16+lh*4..+3] -- this IS the
    // 16x16x16 A-fragment, directly from registers.
    s16x4 pa[2][4];
#pragma unroll
    for (int mi = 0; mi < 2; mi++) {
      float lsum = 0.0f;
#pragma unroll
      for (int ki = 0; ki < 4; ki++) {
        float p0 = exp2f(st[ki][mi][0]);
        float p1 = exp2f(st[ki][mi][1]);
        float p2 = exp2f(st[ki][mi][2]);
        float p3 = exp2f(st[ki][mi][3]);
        lsum += (p0 + p1) + (p2 + p3);
        uint2 t;
        t.x = cvt_pk_bf16(p0, p1);
        t.y = cvt_pk_bf16(p2, p3);
        pa[mi][ki] = __builtin_bit_cast(s16x4, t);
      }
      msum[mi] += lsum;
    }

    // PV: O += P @ V via 16x16x16 MFMAs; V[cur] staged a full tile ago.
    // B-frag: V[key=ki*16+lh*4..+3][d=nd*16+l15] = 4 contiguous bf16 in Vs.
    __builtin_amdgcn_s_setprio(1);
#pragma unroll
    for (int ki = 0; ki < 4; ki++) {
#pragma unroll
      for (int nd = 0; nd < 4; nd++) {
        const int vrow = nd * 16 + l15;
        const int c = ki * 2 + (lh >> 1);
        s16x4 vf = *(const s16x4*)&Vs[cur][vrow * 64 + ((c ^ (vrow & 7)) << 3) +
                                           (lh & 1) * 4];
        acc_o[0][nd] = mfma_16x16x16_bf16(pa[0][ki], vf, acc_o[0][nd]);
        acc_o[1][nd] = mfma_16x16x16_bf16(pa[1][ki], vf, acc_o[1][nd]);
      }
    }
    __builtin_amdgcn_s_setprio(0);

    __syncthreads();   // drains next-tile staging + retires reads of cur
    cur ^= 1;
  }

  // epilogue: reduce per-lane sums, normalize, store
  const int b = bh >> 4, h = bh & 15;
  float rinv[2];
#pragma unroll
  for (int mi = 0; mi < 2; mi++) {
    float s = msum[mi];
    s += __shfl_xor(s, 16, 64);
    s += __shfl_xor(s, 32, 64);
    rinv[mi] = 1.0f / s;
  }
#pragma unroll
  for (int mi = 0; mi < 2; mi++)
#pragma unroll
    for (int r = 0; r < 4; r++) {
      const float rb = __shfl(rinv[mi], (lane & 48) | (lh * 4 + r), 64);
      const int t = qrow0 + mi * 16 + lh * 4 + r;
#pragma unroll
      for (int nd = 0; nd < 4; nd++) {
        const int d = nd * 16 + l15;
        out[(((size_t)b * NT + t) * NH + h) * DK + d] = acc_o[mi][nd][r] * rb;
      }
    }
}

extern "C" void kernel_launch(void* const* d_in, const int* in_sizes, int n_in,
                              void* d_out, int out_size, void* d_ws, size_t ws_size,
                              hipStream_t stream) {
  const float* x = (const float*)d_in[0];
  const float* W = (const float*)d_in[1];
  const float* bias = (const float*)d_in[2];
  float* out = (float*)d_out;
  char* ws = (char*)d_ws;

  unsigned short* Xb = (unsigned short*)(ws);                       // 16.78 MB
  unsigned short* WT = (unsigned short*)(ws + 16777216);            // 6.29 MB
  unsigned short* Q  = (unsigned short*)(ws + 23068672);            // 16.78 MB
  unsigned short* Kd = (unsigned short*)(ws + 39845888);            // 16.78 MB
  unsigned short* VT = (unsigned short*)(ws + 56623104);            // 16.78 MB

  cvt_x_kernel<<<8192, 256, 0, stream>>>(x, Xb);
  transpose_w_kernel<<<dim3(48, 16), 256, 0, stream>>>(W, WT);
  qkv_gemm_kernel<<<1536, 256, 0, stream>>>(Xb, WT, bias, Q, Kd, VT);
  attn_kernel<<<512, 512, 0, stream>>>(Q, Kd, VT, out);
}

// Round 15
// 203.162 us; speedup vs baseline: 1.0293x; 1.0293x over previous
//
#include <hip/hip_runtime.h>
#include <hip/hip_bf16.h>

typedef float f32x4 __attribute__((ext_vector_type(4)));
typedef short s16x8 __attribute__((ext_vector_type(8)));

#define NB 4
#define NT 2048
#define NH 16
#define DK 64
#define DM 1024
#define MTOT (NB * NT)   // 8192
#define NTOT (3 * DM)    // 3072

// log2(e) / sqrt(64)
#define QSCALE 0.18033688011112042f

__device__ __forceinline__ unsigned short f2bf(float f) {
  union { float f; unsigned u; } v; v.f = f;
  unsigned r = v.u + 0x7fff + ((v.u >> 16) & 1);
  return (unsigned short)(r >> 16);
}

__device__ __forceinline__ unsigned cvt_pk_bf16(float a, float b) {
  unsigned r;
  asm("v_cvt_pk_bf16_f32 %0, %1, %2" : "=v"(r) : "v"(a), "v"(b));
  return r;
}

__device__ __forceinline__ void async_copy16(void* lds, const void* g) {
  __builtin_amdgcn_global_load_lds(
      (const __attribute__((address_space(1))) unsigned int*)g,
      (__attribute__((address_space(3))) unsigned int*)lds, 16, 0, 0);
}

// ---------------- fused prep: x -> bf16  AND  W -> WT bf16 -------------------
// blocks [0, 8192): cvt_x (256 threads x 4 floats). blocks [8192, 8960):
// transpose_w 64x64 tiles (768 = 48 x 16).
__global__ void prep_kernel(const float* __restrict__ x,
                            unsigned short* __restrict__ xb,
                            const float* __restrict__ W,
                            unsigned short* __restrict__ WT) {
  if (blockIdx.x < 8192) {
    int i = (blockIdx.x * 256 + threadIdx.x) * 4;
    float4 v = *reinterpret_cast<const float4*>(x + i);
    ushort4 o;
    o.x = f2bf(v.x); o.y = f2bf(v.y); o.z = f2bf(v.z); o.w = f2bf(v.w);
    *reinterpret_cast<ushort4*>(xb + i) = o;
  } else {
    __shared__ float tile[64][65];
    const int bb = blockIdx.x - 8192;
    const int n0 = (bb % 48) * 64;   // over 3072
    const int k0 = (bb / 48) * 64;   // over 1024
    const int t = threadIdx.x;       // 256
    const int col = t & 63;
    const int rw = t >> 6;
#pragma unroll
    for (int r = 0; r < 16; r++) {
      int row = r * 4 + rw;          // k offset
      tile[row][col] = W[(size_t)(k0 + row) * NTOT + n0 + col];
    }
    __syncthreads();
#pragma unroll
    for (int r = 0; r < 16; r++) {
      int row = r * 4 + rw;          // n offset
      WT[(size_t)(n0 + row) * DM + k0 + col] = f2bf(tile[col][row]);
    }
  }
}

// ---------------- QKV GEMM (2-phase pipelined + XCD swizzle) -----------------
__global__ __launch_bounds__(256) void qkv_gemm_kernel(
    const unsigned short* __restrict__ A, const unsigned short* __restrict__ BT,
    const float* __restrict__ bias, unsigned short* __restrict__ Q,
    unsigned short* __restrict__ Kd, unsigned short* __restrict__ VT) {
  __shared__ unsigned short As[2][128 * 32];
  __shared__ unsigned short Bs[2][128 * 32];
  const int tid = threadIdx.x;
  const int lane = tid & 63;
  const int wave = tid >> 6;
  const int wr = wave >> 1, wc = wave & 1;
  const int l15 = lane & 15, lh = lane >> 4;

  // XCD-chunked swizzle: 1536 blocks, 8 XCDs -> XCD x owns orig [x*192,(x+1)*192)
  // -> each XCD's L2 sees 8 A-panels (2MB) + B panels, instead of scatter.
  const int orig = ((blockIdx.x & 7) * 192) + (blockIdx.x >> 3);
  const int nTilesN = NTOT / 128;  // 24
  const int tm = (orig / nTilesN) * 128;
  const int tn = (orig % nTilesN) * 128;

  const int srow = (tid >> 2), scol = (tid & 3) << 3;
  const int srow2 = ((256 + tid) >> 2), scol2 = ((256 + tid) & 3) << 3;

  f32x4 acc[4][4] = {};

  async_copy16(&As[0][(wave * 64) * 8], &A[(size_t)(tm + srow) * DM + scol]);
  async_copy16(&Bs[0][(wave * 64) * 8], &BT[(size_t)(tn + srow) * DM + scol]);
  async_copy16(&As[0][(256 + wave * 64) * 8], &A[(size_t)(tm + srow2) * DM + scol2]);
  async_copy16(&Bs[0][(256 + wave * 64) * 8], &BT[(size_t)(tn + srow2) * DM + scol2]);
  __syncthreads();

  int cur = 0;
  for (int k0 = 0; k0 < DM; k0 += 32) {
    if (k0 + 32 < DM) {
      const int nb = cur ^ 1, kn = k0 + 32;
      async_copy16(&As[nb][(wave * 64) * 8], &A[(size_t)(tm + srow) * DM + kn + scol]);
      async_copy16(&Bs[nb][(wave * 64) * 8], &BT[(size_t)(tn + srow) * DM + kn + scol]);
      async_copy16(&As[nb][(256 + wave * 64) * 8], &A[(size_t)(tm + srow2) * DM + kn + scol2]);
      async_copy16(&Bs[nb][(256 + wave * 64) * 8], &BT[(size_t)(tn + srow2) * DM + kn + scol2]);
    }
    s16x8 af[4], bf[4];
#pragma unroll
    for (int mi = 0; mi < 4; mi++)
      af[mi] = *(const s16x8*)&As[cur][(wr * 64 + mi * 16 + l15) * 32 + lh * 8];
#pragma unroll
    for (int ni = 0; ni < 4; ni++)
      bf[ni] = *(const s16x8*)&Bs[cur][(wc * 64 + ni * 16 + l15) * 32 + lh * 8];
    __builtin_amdgcn_s_setprio(1);
#pragma unroll
    for (int mi = 0; mi < 4; mi++)
#pragma unroll
      for (int ni = 0; ni < 4; ni++)
        acc[mi][ni] = __builtin_amdgcn_mfma_f32_16x16x32_bf16(
            af[mi], bf[ni], acc[mi][ni], 0, 0, 0);
    __builtin_amdgcn_s_setprio(0);
    __syncthreads();
    cur ^= 1;
  }

  // epilogue: bias + scatter
  const int part = tn >> 10;  // 0=Q 1=K 2=V (uniform per block)
#pragma unroll
  for (int ni = 0; ni < 4; ni++) {
    const int n = tn + wc * 64 + ni * 16 + l15;
    const float bv = bias[n];
    const int n1 = n & 1023;
    const int h = n1 >> 6, d = n1 & 63;
#pragma unroll
    for (int mi = 0; mi < 4; mi++) {
#pragma unroll
      for (int r = 0; r < 4; r++) {
        const int m = tm + wr * 64 + mi * 16 + lh * 4 + r;
        const int b = m >> 11, t = m & 2047;
        float v = acc[mi][ni][r] + bv;
        if (part == 0) {
          v *= QSCALE;
          Q[((size_t)(b * NH + h) * NT + t) * DK + d] = f2bf(v);
        } else if (part == 1) {
          Kd[((size_t)(b * NH + h) * NT + t) * DK + d] = f2bf(v);
        } else {
          VT[((size_t)(b * NH + h) * DK + d) * NT + t] = f2bf(v);
        }
      }
    }
  }
}

// ---------------- Flash attention v10 (r13 exact: best known, 118.7us) -------
// 8-wave/512-thread blocks, shift-free softmax, K/V double-buffered, ONE
// barrier per tile, XCD swizzle, setprio. PV via 16x16x32 through per-wave
// Ps half-buffers (r14's K=16 register-PV was slower: 2x MFMA-pipe cycles +
// 2x bank conflicts).
// Q,K: (BH,T,64) bf16 (Q pre-scaled); VT: (BH,64,T) bf16; out fp32 (B,T,H,64).
// K/V swizzle: 16B chunk c of row at c^(row&7) (pre-swizzled global source,
// linear LDS dest). Ps swizzle: chunk c at c^((row>>1)&3).
__global__ __launch_bounds__(512) void attn_kernel(
    const unsigned short* __restrict__ Q, const unsigned short* __restrict__ K,
    const unsigned short* __restrict__ VT, float* __restrict__ out) {
  __shared__ unsigned short Ks[2][64 * 64];   // [buf][key][d]  2x8KB
  __shared__ unsigned short Vs[2][64 * 64];   // [buf][d][key]  2x8KB
  __shared__ unsigned short Ps[8][32 * 32];   // per-wave P half 16KB

  const int tid = threadIdx.x, lane = tid & 63, wave = tid >> 6;
  const int l15 = lane & 15, lh = lane >> 4;
  // XCD swizzle: 512 blocks, 8 XCDs -> XCD x gets orig ids [x*64, x*64+64)
  const int orig = ((blockIdx.x & 7) << 6) + (blockIdx.x >> 3);
  const int bh = orig >> 3;         // 64 (b,h) pairs
  const int qt = orig & 7;          // 8 q-tiles of 256 rows
  const size_t base = (size_t)bh * NT * DK;
  const int qrow0 = qt * 256 + wave * 32;

  // staging geometry: 512 threads cover one 64x64 bf16 tile (1 chunk each)
  const int srow = tid >> 3, schunk = tid & 7;
  const int ssw = ((schunk ^ (srow & 7)) << 3);

  // Q fragments (MFMA B operand): Q[query=l15][d=lh*8..]
  s16x8 qf[2][2];
#pragma unroll
  for (int mi = 0; mi < 2; mi++)
#pragma unroll
    for (int kk = 0; kk < 2; kk++)
      qf[mi][kk] = *(const s16x8*)&Q[base + (size_t)(qrow0 + mi * 16 + l15) * DK +
                                     kk * 32 + lh * 8];

  float msum[2] = {0.0f, 0.0f};
  f32x4 acc_o[2][4] = {};

  // prologue: stage K[0], V[0] into buf 0
  async_copy16(&Ks[0][(wave * 64) * 8], &K[base + (size_t)srow * DK + ssw]);
  async_copy16(&Vs[0][(wave * 64) * 8], &VT[base + (size_t)srow * NT + ssw]);
  __syncthreads();

  int cur = 0;
  for (int j = 0; j < NT; j += 64) {
    // prefetch NEXT tile's K and V into the ^1 buffers
    if (j + 64 < NT) {
      async_copy16(&Ks[cur ^ 1][(wave * 64) * 8],
                   &K[base + (size_t)(j + 64 + srow) * DK + ssw]);
      async_copy16(&Vs[cur ^ 1][(wave * 64) * 8],
                   &VT[base + (size_t)srow * NT + j + 64 + ssw]);
    }

    // S^T = K @ Q^T : st[ki][mi] rows=keys(ki*16+lh*4+r), cols=queries(mi*16+l15)
    f32x4 st[4][2] = {};
    __builtin_amdgcn_s_setprio(1);
#pragma unroll
    for (int ki = 0; ki < 4; ki++) {
      const int row = ki * 16 + l15;
      const unsigned short* kr = &Ks[cur][row * 64];
      s16x8 kf0 = *(const s16x8*)&kr[((lh ^ (row & 7)) << 3)];
      s16x8 kf1 = *(const s16x8*)&kr[(((4 + lh) ^ (row & 7)) << 3)];
#pragma unroll
      for (int mi = 0; mi < 2; mi++) {
        st[ki][mi] = __builtin_amdgcn_mfma_f32_16x16x32_bf16(kf0, qf[mi][0], st[ki][mi], 0, 0, 0);
        st[ki][mi] = __builtin_amdgcn_mfma_f32_16x16x32_bf16(kf1, qf[mi][1], st[ki][mi], 0, 0, 0);
      }
    }
    __builtin_amdgcn_s_setprio(0);

    // shift-free softmax: p = exp2(s); per-lane partial sums; pack bf16 pairs
    uint2 pw[2][4];   // [mi][ki]
#pragma unroll
    for (int mi = 0; mi < 2; mi++) {
      float lsum = 0.0f;
#pragma unroll
      for (int ki = 0; ki < 4; ki++) {
        float p0 = exp2f(st[ki][mi][0]);
        float p1 = exp2f(st[ki][mi][1]);
        float p2 = exp2f(st[ki][mi][2]);
        float p3 = exp2f(st[ki][mi][3]);
        lsum += (p0 + p1) + (p2 + p3);
        pw[mi][ki].x = cvt_pk_bf16(p0, p1);
        pw[mi][ki].y = cvt_pk_bf16(p2, p3);
      }
      msum[mi] += lsum;
    }

    // PV: P(32x64) @ V(64x64) in two kk-halves through the 2KB/wave Ps buffer
    // (V[cur] was staged a full tile ago -> no wait needed)
#pragma unroll
    for (int kk = 0; kk < 2; kk++) {
#pragma unroll
      for (int mi = 0; mi < 2; mi++) {
        const int row = mi * 16 + l15;
#pragma unroll
        for (int k2 = 0; k2 < 2; k2++) {
          const int cw = k2 * 2 + (lh >> 1);
          *(uint2*)&Ps[wave][row * 32 + ((cw ^ ((row >> 1) & 3)) << 3) +
                             (lh & 1) * 4] = pw[mi][kk * 2 + k2];
        }
      }
      const int r0 = l15, r1 = 16 + l15;
      s16x8 pa0 = *(const s16x8*)&Ps[wave][r0 * 32 + ((lh ^ ((r0 >> 1) & 3)) << 3)];
      s16x8 pa1 = *(const s16x8*)&Ps[wave][r1 * 32 + ((lh ^ ((r1 >> 1) & 3)) << 3)];
      __builtin_amdgcn_s_setprio(1);
#pragma unroll
      for (int nd = 0; nd < 4; nd++) {
        const int vrow = nd * 16 + l15;
        s16x8 vf = *(const s16x8*)&Vs[cur][vrow * 64 + (((kk * 4 + lh) ^ (vrow & 7)) << 3)];
        acc_o[0][nd] = __builtin_amdgcn_mfma_f32_16x16x32_bf16(pa0, vf, acc_o[0][nd], 0, 0, 0);
        acc_o[1][nd] = __builtin_amdgcn_mfma_f32_16x16x32_bf16(pa1, vf, acc_o[1][nd], 0, 0, 0);
      }
      __builtin_amdgcn_s_setprio(0);
    }

    __syncthreads();   // drains next-tile staging + retires reads of cur
    cur ^= 1;
  }

  // epilogue: reduce per-lane sums, normalize, store
  const int b = bh >> 4, h = bh & 15;
  float rinv[2];
#pragma unroll
  for (int mi = 0; mi < 2; mi++) {
    float s = msum[mi];
    s += __shfl_xor(s, 16, 64);
    s += __shfl_xor(s, 32, 64);
    rinv[mi] = 1.0f / s;
  }
#pragma unroll
  for (int mi = 0; mi < 2; mi++)
#pragma unroll
    for (int r = 0; r < 4; r++) {
      const float rb = __shfl(rinv[mi], (lane & 48) | (lh * 4 + r), 64);
      const int t = qrow0 + mi * 16 + lh * 4 + r;
#pragma unroll
      for (int nd = 0; nd < 4; nd++) {
        const int d = nd * 16 + l15;
        out[(((size_t)b * NT + t) * NH + h) * DK + d] = acc_o[mi][nd][r] * rb;
      }
    }
}

extern "C" void kernel_launch(void* const* d_in, const int* in_sizes, int n_in,
                              void* d_out, int out_size, void* d_ws, size_t ws_size,
                              hipStream_t stream) {
  const float* x = (const float*)d_in[0];
  const float* W = (const float*)d_in[1];
  const float* bias = (const float*)d_in[2];
  float* out = (float*)d_out;
  char* ws = (char*)d_ws;

  unsigned short* Xb = (unsigned short*)(ws);                       // 16.78 MB
  unsigned short* WT = (unsigned short*)(ws + 16777216);            // 6.29 MB
  unsigned short* Q  = (unsigned short*)(ws + 23068672);            // 16.78 MB
  unsigned short* Kd = (unsigned short*)(ws + 39845888);            // 16.78 MB
  unsigned short* VT = (unsigned short*)(ws + 56623104);            // 16.78 MB

  prep_kernel<<<8960, 256, 0, stream>>>(x, Xb, W, WT);
  qkv_gemm_kernel<<<1536, 256, 0, stream>>>(Xb, WT, bias, Q, Kd, VT);
  attn_kernel<<<512, 512, 0, stream>>>(Q, Kd, VT, out);
}

// Round 16
// 199.532 us; speedup vs baseline: 1.0480x; 1.0182x over previous
//
#include <hip/hip_runtime.h>
#include <hip/hip_bf16.h>

typedef float f32x4 __attribute__((ext_vector_type(4)));
typedef short s16x8 __attribute__((ext_vector_type(8)));

#define NB 4
#define NT 2048
#define NH 16
#define DK 64
#define DM 1024
#define MTOT (NB * NT)   // 8192
#define NTOT (3 * DM)    // 3072

// log2(e) / sqrt(64)
#define QSCALE 0.18033688011112042f

__device__ __forceinline__ unsigned short f2bf(float f) {
  union { float f; unsigned u; } v; v.f = f;
  unsigned r = v.u + 0x7fff + ((v.u >> 16) & 1);
  return (unsigned short)(r >> 16);
}

__device__ __forceinline__ unsigned cvt_pk_bf16(float a, float b) {
  unsigned r;
  asm("v_cvt_pk_bf16_f32 %0, %1, %2" : "=v"(r) : "v"(a), "v"(b));
  return r;
}

__device__ __forceinline__ void async_copy16(void* lds, const void* g) {
  __builtin_amdgcn_global_load_lds(
      (const __attribute__((address_space(1))) unsigned int*)g,
      (__attribute__((address_space(3))) unsigned int*)lds, 16, 0, 0);
}

// ---------------- fused prep: x -> bf16  AND  W -> WT bf16 -------------------
__global__ void prep_kernel(const float* __restrict__ x,
                            unsigned short* __restrict__ xb,
                            const float* __restrict__ W,
                            unsigned short* __restrict__ WT) {
  if (blockIdx.x < 8192) {
    int i = (blockIdx.x * 256 + threadIdx.x) * 4;
    float4 v = *reinterpret_cast<const float4*>(x + i);
    ushort4 o;
    o.x = f2bf(v.x); o.y = f2bf(v.y); o.z = f2bf(v.z); o.w = f2bf(v.w);
    *reinterpret_cast<ushort4*>(xb + i) = o;
  } else {
    __shared__ float tile[64][65];
    const int bb = blockIdx.x - 8192;
    const int n0 = (bb % 48) * 64;   // over 3072
    const int k0 = (bb / 48) * 64;   // over 1024
    const int t = threadIdx.x;       // 256
    const int col = t & 63;
    const int rw = t >> 6;
#pragma unroll
    for (int r = 0; r < 16; r++) {
      int row = r * 4 + rw;          // k offset
      tile[row][col] = W[(size_t)(k0 + row) * NTOT + n0 + col];
    }
    __syncthreads();
#pragma unroll
    for (int r = 0; r < 16; r++) {
      int row = r * 4 + rw;          // n offset
      WT[(size_t)(n0 + row) * DM + k0 + col] = f2bf(tile[col][row]);
    }
  }
}

// ---------------- QKV GEMM (2-phase pipelined + XCD swizzle) -----------------
__global__ __launch_bounds__(256) void qkv_gemm_kernel(
    const unsigned short* __restrict__ A, const unsigned short* __restrict__ BT,
    const float* __restrict__ bias, unsigned short* __restrict__ Q,
    unsigned short* __restrict__ Kd, unsigned short* __restrict__ VT) {
  __shared__ unsigned short As[2][128 * 32];
  __shared__ unsigned short Bs[2][128 * 32];
  const int tid = threadIdx.x;
  const int lane = tid & 63;
  const int wave = tid >> 6;
  const int wr = wave >> 1, wc = wave & 1;
  const int l15 = lane & 15, lh = lane >> 4;

  const int orig = ((blockIdx.x & 7) * 192) + (blockIdx.x >> 3);
  const int nTilesN = NTOT / 128;  // 24
  const int tm = (orig / nTilesN) * 128;
  const int tn = (orig % nTilesN) * 128;

  const int srow = (tid >> 2), scol = (tid & 3) << 3;
  const int srow2 = ((256 + tid) >> 2), scol2 = ((256 + tid) & 3) << 3;

  f32x4 acc[4][4] = {};

  async_copy16(&As[0][(wave * 64) * 8], &A[(size_t)(tm + srow) * DM + scol]);
  async_copy16(&Bs[0][(wave * 64) * 8], &BT[(size_t)(tn + srow) * DM + scol]);
  async_copy16(&As[0][(256 + wave * 64) * 8], &A[(size_t)(tm + srow2) * DM + scol2]);
  async_copy16(&Bs[0][(256 + wave * 64) * 8], &BT[(size_t)(tn + srow2) * DM + scol2]);
  __syncthreads();

  int cur = 0;
  for (int k0 = 0; k0 < DM; k0 += 32) {
    if (k0 + 32 < DM) {
      const int nb = cur ^ 1, kn = k0 + 32;
      async_copy16(&As[nb][(wave * 64) * 8], &A[(size_t)(tm + srow) * DM + kn + scol]);
      async_copy16(&Bs[nb][(wave * 64) * 8], &BT[(size_t)(tn + srow) * DM + kn + scol]);
      async_copy16(&As[nb][(256 + wave * 64) * 8], &A[(size_t)(tm + srow2) * DM + kn + scol2]);
      async_copy16(&Bs[nb][(256 + wave * 64) * 8], &BT[(size_t)(tn + srow2) * DM + kn + scol2]);
    }
    s16x8 af[4], bf[4];
#pragma unroll
    for (int mi = 0; mi < 4; mi++)
      af[mi] = *(const s16x8*)&As[cur][(wr * 64 + mi * 16 + l15) * 32 + lh * 8];
#pragma unroll
    for (int ni = 0; ni < 4; ni++)
      bf[ni] = *(const s16x8*)&Bs[cur][(wc * 64 + ni * 16 + l15) * 32 + lh * 8];
    __builtin_amdgcn_s_setprio(1);
#pragma unroll
    for (int mi = 0; mi < 4; mi++)
#pragma unroll
      for (int ni = 0; ni < 4; ni++)
        acc[mi][ni] = __builtin_amdgcn_mfma_f32_16x16x32_bf16(
            af[mi], bf[ni], acc[mi][ni], 0, 0, 0);
    __builtin_amdgcn_s_setprio(0);
    __syncthreads();
    cur ^= 1;
  }

  // epilogue: bias + scatter
  const int part = tn >> 10;  // 0=Q 1=K 2=V (uniform per block)
#pragma unroll
  for (int ni = 0; ni < 4; ni++) {
    const int n = tn + wc * 64 + ni * 16 + l15;
    const float bv = bias[n];
    const int n1 = n & 1023;
    const int h = n1 >> 6, d = n1 & 63;
#pragma unroll
    for (int mi = 0; mi < 4; mi++) {
#pragma unroll
      for (int r = 0; r < 4; r++) {
        const int m = tm + wr * 64 + mi * 16 + lh * 4 + r;
        const int b = m >> 11, t = m & 2047;
        float v = acc[mi][ni][r] + bv;
        if (part == 0) {
          v *= QSCALE;
          Q[((size_t)(b * NH + h) * NT + t) * DK + d] = f2bf(v);
        } else if (part == 1) {
          Kd[((size_t)(b * NH + h) * NT + t) * DK + d] = f2bf(v);
        } else {
          VT[((size_t)(b * NH + h) * DK + d) * NT + t] = f2bf(v);
        }
      }
    }
  }
}

// ---------------- Flash attention v12 (counted vmcnt + MFMA rowsum) ----------
// r13 structure (8-wave/512-thread, shift-free softmax, K/V dbuf, XCD swizzle,
// setprio) with:
//  1. T4 counted-vmcnt barriers: raw s_barrier pairs + s_waitcnt vmcnt(2) --
//     wait only for the TILE-OLD loads; the just-issued j+1 loads stay in
//     flight across both barriers (no vmcnt(0)/lgkmcnt(0) drain per tile).
//  2. Softmax denominator via MFMA: acc_s += mfma(pa, ones) -- C/D layout
//     lands rowsum at exactly acc_o's [mi][r] -> lane-local normalize, no
//     shfl reduce/broadcast; 24 VALU adds/tile -> 4 MFMA/tile.
// Q,K: (BH,T,64) bf16 (Q pre-scaled); VT: (BH,64,T) bf16; out fp32 (B,T,H,64).
// K/V swizzle: 16B chunk c of row at c^(row&7) (pre-swizzled global source,
// linear LDS dest). Ps swizzle: chunk c at c^((row>>1)&3).
__global__ __launch_bounds__(512) void attn_kernel(
    const unsigned short* __restrict__ Q, const unsigned short* __restrict__ K,
    const unsigned short* __restrict__ VT, float* __restrict__ out) {
  __shared__ unsigned short Ks[2][64 * 64];   // [buf][key][d]  2x8KB
  __shared__ unsigned short Vs[2][64 * 64];   // [buf][d][key]  2x8KB
  __shared__ unsigned short Ps[8][32 * 32];   // per-wave P half 16KB

  const int tid = threadIdx.x, lane = tid & 63, wave = tid >> 6;
  const int l15 = lane & 15, lh = lane >> 4;
  const int orig = ((blockIdx.x & 7) << 6) + (blockIdx.x >> 3);
  const int bh = orig >> 3;         // 64 (b,h) pairs
  const int qt = orig & 7;          // 8 q-tiles of 256 rows
  const size_t base = (size_t)bh * NT * DK;
  const int qrow0 = qt * 256 + wave * 32;

  const int srow = tid >> 3, schunk = tid & 7;
  const int ssw = ((schunk ^ (srow & 7)) << 3);

  // Q fragments (MFMA B operand): Q[query=l15][d=lh*8..]
  s16x8 qf[2][2];
#pragma unroll
  for (int mi = 0; mi < 2; mi++)
#pragma unroll
    for (int kk = 0; kk < 2; kk++)
      qf[mi][kk] = *(const s16x8*)&Q[base + (size_t)(qrow0 + mi * 16 + l15) * DK +
                                     kk * 32 + lh * 8];

  f32x4 acc_o[2][4] = {};
  f32x4 acc_s[2] = {};   // rowsum accumulators (denominator)
  const s16x8 ones = {16256, 16256, 16256, 16256, 16256, 16256, 16256, 16256};

  // prologue: ISSUE K[0],V[0] into buf 0 (no wait; loop handles it)
  async_copy16(&Ks[0][(wave * 64) * 8], &K[base + (size_t)srow * DK + ssw]);
  async_copy16(&Vs[0][(wave * 64) * 8], &VT[base + (size_t)srow * NT + ssw]);

  int cur = 0;
  for (int j = 0; j < NT; j += 64) {
    // issue NEXT tile's loads, then wait only for the TILE-OLD pair
    if (j + 64 < NT) {
      async_copy16(&Ks[cur ^ 1][(wave * 64) * 8],
                   &K[base + (size_t)(j + 64 + srow) * DK + ssw]);
      async_copy16(&Vs[cur ^ 1][(wave * 64) * 8],
                   &VT[base + (size_t)srow * NT + j + 64 + ssw]);
      asm volatile("s_waitcnt vmcnt(2)" ::: "memory");
    } else {
      asm volatile("s_waitcnt vmcnt(0)" ::: "memory");
    }
    __builtin_amdgcn_s_barrier();        // all waves' tile-j data in LDS
    __builtin_amdgcn_sched_barrier(0);

    // S^T = K @ Q^T : st[ki][mi] rows=keys(ki*16+lh*4+r), cols=queries(mi*16+l15)
    f32x4 st[4][2] = {};
    __builtin_amdgcn_s_setprio(1);
#pragma unroll
    for (int ki = 0; ki < 4; ki++) {
      const int row = ki * 16 + l15;
      const unsigned short* kr = &Ks[cur][row * 64];
      s16x8 kf0 = *(const s16x8*)&kr[((lh ^ (row & 7)) << 3)];
      s16x8 kf1 = *(const s16x8*)&kr[(((4 + lh) ^ (row & 7)) << 3)];
#pragma unroll
      for (int mi = 0; mi < 2; mi++) {
        st[ki][mi] = __builtin_amdgcn_mfma_f32_16x16x32_bf16(kf0, qf[mi][0], st[ki][mi], 0, 0, 0);
        st[ki][mi] = __builtin_amdgcn_mfma_f32_16x16x32_bf16(kf1, qf[mi][1], st[ki][mi], 0, 0, 0);
      }
    }
    __builtin_amdgcn_s_setprio(0);

    // shift-free softmax: p = exp2(s); pack bf16 pairs (no scalar row-sums)
    uint2 pw[2][4];   // [mi][ki]
#pragma unroll
    for (int mi = 0; mi < 2; mi++) {
#pragma unroll
      for (int ki = 0; ki < 4; ki++) {
        float p0 = exp2f(st[ki][mi][0]);
        float p1 = exp2f(st[ki][mi][1]);
        float p2 = exp2f(st[ki][mi][2]);
        float p3 = exp2f(st[ki][mi][3]);
        pw[mi][ki].x = cvt_pk_bf16(p0, p1);
        pw[mi][ki].y = cvt_pk_bf16(p2, p3);
      }
    }

    // PV + denominator: two kk-halves through the 2KB/wave Ps buffer
#pragma unroll
    for (int kk = 0; kk < 2; kk++) {
#pragma unroll
      for (int mi = 0; mi < 2; mi++) {
        const int row = mi * 16 + l15;
#pragma unroll
        for (int k2 = 0; k2 < 2; k2++) {
          const int cw = k2 * 2 + (lh >> 1);
          *(uint2*)&Ps[wave][row * 32 + ((cw ^ ((row >> 1) & 3)) << 3) +
                             (lh & 1) * 4] = pw[mi][kk * 2 + k2];
        }
      }
      const int r0 = l15, r1 = 16 + l15;
      s16x8 pa0 = *(const s16x8*)&Ps[wave][r0 * 32 + ((lh ^ ((r0 >> 1) & 3)) << 3)];
      s16x8 pa1 = *(const s16x8*)&Ps[wave][r1 * 32 + ((lh ^ ((r1 >> 1) & 3)) << 3)];
      __builtin_amdgcn_s_setprio(1);
      acc_s[0] = __builtin_amdgcn_mfma_f32_16x16x32_bf16(pa0, ones, acc_s[0], 0, 0, 0);
      acc_s[1] = __builtin_amdgcn_mfma_f32_16x16x32_bf16(pa1, ones, acc_s[1], 0, 0, 0);
#pragma unroll
      for (int nd = 0; nd < 4; nd++) {
        const int vrow = nd * 16 + l15;
        s16x8 vf = *(const s16x8*)&Vs[cur][vrow * 64 + (((kk * 4 + lh) ^ (vrow & 7)) << 3)];
        acc_o[0][nd] = __builtin_amdgcn_mfma_f32_16x16x32_bf16(pa0, vf, acc_o[0][nd], 0, 0, 0);
        acc_o[1][nd] = __builtin_amdgcn_mfma_f32_16x16x32_bf16(pa1, vf, acc_o[1][nd], 0, 0, 0);
      }
      __builtin_amdgcn_s_setprio(0);
    }

    __builtin_amdgcn_s_barrier();        // all waves done reading cur; next
    __builtin_amdgcn_sched_barrier(0);   // iter may issue into it
    cur ^= 1;
  }

  // epilogue: lane-local normalize (acc_s[mi][r] aligns with acc_o[mi][nd][r])
  const int b = bh >> 4, h = bh & 15;
#pragma unroll
  for (int mi = 0; mi < 2; mi++)
#pragma unroll
    for (int r = 0; r < 4; r++) {
      const float rb = 1.0f / acc_s[mi][r];
      const int t = qrow0 + mi * 16 + lh * 4 + r;
#pragma unroll
      for (int nd = 0; nd < 4; nd++) {
        const int d = nd * 16 + l15;
        out[(((size_t)b * NT + t) * NH + h) * DK + d] = acc_o[mi][nd][r] * rb;
      }
    }
}

extern "C" void kernel_launch(void* const* d_in, const int* in_sizes, int n_in,
                              void* d_out, int out_size, void* d_ws, size_t ws_size,
                              hipStream_t stream) {
  const float* x = (const float*)d_in[0];
  const float* W = (const float*)d_in[1];
  const float* bias = (const float*)d_in[2];
  float* out = (float*)d_out;
  char* ws = (char*)d_ws;

  unsigned short* Xb = (unsigned short*)(ws);                       // 16.78 MB
  unsigned short* WT = (unsigned short*)(ws + 16777216);            // 6.29 MB
  unsigned short* Q  = (unsigned short*)(ws + 23068672);            // 16.78 MB
  unsigned short* Kd = (unsigned short*)(ws + 39845888);            // 16.78 MB
  unsigned short* VT = (unsigned short*)(ws + 56623104);            // 16.78 MB

  prep_kernel<<<8960, 256, 0, stream>>>(x, Xb, W, WT);
  qkv_gemm_kernel<<<1536, 256, 0, stream>>>(Xb, WT, bias, Q, Kd, VT);
  attn_kernel<<<512, 512, 0, stream>>>(Q, Kd, VT, out);
}

// Round 17
// 196.089 us; speedup vs baseline: 1.0664x; 1.0176x over previous
//
#include <hip/hip_runtime.h>
#include <hip/hip_bf16.h>

typedef float f32x4 __attribute__((ext_vector_type(4)));
typedef short s16x8 __attribute__((ext_vector_type(8)));

#define NB 4
#define NT 2048
#define NH 16
#define DK 64
#define DM 1024
#define MTOT (NB * NT)   // 8192
#define NTOT (3 * DM)    // 3072

// log2(e) / sqrt(64)
#define QSCALE 0.18033688011112042f

__device__ __forceinline__ unsigned short f2bf(float f) {
  union { float f; unsigned u; } v; v.f = f;
  unsigned r = v.u + 0x7fff + ((v.u >> 16) & 1);
  return (unsigned short)(r >> 16);
}

__device__ __forceinline__ unsigned cvt_pk_bf16(float a, float b) {
  unsigned r;
  asm("v_cvt_pk_bf16_f32 %0, %1, %2" : "=v"(r) : "v"(a), "v"(b));
  return r;
}

__device__ __forceinline__ void async_copy16(void* lds, const void* g) {
  __builtin_amdgcn_global_load_lds(
      (const __attribute__((address_space(1))) unsigned int*)g,
      (__attribute__((address_space(3))) unsigned int*)lds, 16, 0, 0);
}

// ---------------- fused prep: x -> bf16  AND  W -> WT bf16 -------------------
__global__ void prep_kernel(const float* __restrict__ x,
                            unsigned short* __restrict__ xb,
                            const float* __restrict__ W,
                            unsigned short* __restrict__ WT) {
  if (blockIdx.x < 8192) {
    int i = (blockIdx.x * 256 + threadIdx.x) * 4;
    float4 v = *reinterpret_cast<const float4*>(x + i);
    ushort4 o;
    o.x = f2bf(v.x); o.y = f2bf(v.y); o.z = f2bf(v.z); o.w = f2bf(v.w);
    *reinterpret_cast<ushort4*>(xb + i) = o;
  } else {
    __shared__ float tile[64][65];
    const int bb = blockIdx.x - 8192;
    const int n0 = (bb % 48) * 64;   // over 3072
    const int k0 = (bb / 48) * 64;   // over 1024
    const int t = threadIdx.x;       // 256
    const int col = t & 63;
    const int rw = t >> 6;
#pragma unroll
    for (int r = 0; r < 16; r++) {
      int row = r * 4 + rw;          // k offset
      tile[row][col] = W[(size_t)(k0 + row) * NTOT + n0 + col];
    }
    __syncthreads();
#pragma unroll
    for (int r = 0; r < 16; r++) {
      int row = r * 4 + rw;          // n offset
      WT[(size_t)(n0 + row) * DM + k0 + col] = f2bf(tile[col][row]);
    }
  }
}

// ---------------- QKV GEMM (counted-vmcnt pipeline + XCD swizzle) ------------
// r16-attn's proven pattern ported: per K-step issue 4 next-tile
// global_load_lds, s_waitcnt vmcnt(4) (wait only the tile-old loads), raw
// s_barrier, compute, raw s_barrier. No per-step vmcnt(0)/lgkmcnt(0) drain.
__global__ __launch_bounds__(256) void qkv_gemm_kernel(
    const unsigned short* __restrict__ A, const unsigned short* __restrict__ BT,
    const float* __restrict__ bias, unsigned short* __restrict__ Q,
    unsigned short* __restrict__ Kd, unsigned short* __restrict__ VT) {
  __shared__ unsigned short As[2][128 * 32];
  __shared__ unsigned short Bs[2][128 * 32];
  const int tid = threadIdx.x;
  const int lane = tid & 63;
  const int wave = tid >> 6;
  const int wr = wave >> 1, wc = wave & 1;
  const int l15 = lane & 15, lh = lane >> 4;

  const int orig = ((blockIdx.x & 7) * 192) + (blockIdx.x >> 3);
  const int nTilesN = NTOT / 128;  // 24
  const int tm = (orig / nTilesN) * 128;
  const int tn = (orig % nTilesN) * 128;

  const int srow = (tid >> 2), scol = (tid & 3) << 3;
  const int srow2 = ((256 + tid) >> 2), scol2 = ((256 + tid) & 3) << 3;

  f32x4 acc[4][4] = {};

  // prologue: ISSUE tile-0 loads (no wait; loop's vmcnt handles it)
  async_copy16(&As[0][(wave * 64) * 8], &A[(size_t)(tm + srow) * DM + scol]);
  async_copy16(&Bs[0][(wave * 64) * 8], &BT[(size_t)(tn + srow) * DM + scol]);
  async_copy16(&As[0][(256 + wave * 64) * 8], &A[(size_t)(tm + srow2) * DM + scol2]);
  async_copy16(&Bs[0][(256 + wave * 64) * 8], &BT[(size_t)(tn + srow2) * DM + scol2]);

  int cur = 0;
  for (int k0 = 0; k0 < DM; k0 += 32) {
    if (k0 + 32 < DM) {
      const int nb = cur ^ 1, kn = k0 + 32;
      async_copy16(&As[nb][(wave * 64) * 8], &A[(size_t)(tm + srow) * DM + kn + scol]);
      async_copy16(&Bs[nb][(wave * 64) * 8], &BT[(size_t)(tn + srow) * DM + kn + scol]);
      async_copy16(&As[nb][(256 + wave * 64) * 8], &A[(size_t)(tm + srow2) * DM + kn + scol2]);
      async_copy16(&Bs[nb][(256 + wave * 64) * 8], &BT[(size_t)(tn + srow2) * DM + kn + scol2]);
      asm volatile("s_waitcnt vmcnt(4)" ::: "memory");
    } else {
      asm volatile("s_waitcnt vmcnt(0)" ::: "memory");
    }
    __builtin_amdgcn_s_barrier();        // tile-k data visible to all waves
    __builtin_amdgcn_sched_barrier(0);

    s16x8 af[4], bf[4];
#pragma unroll
    for (int mi = 0; mi < 4; mi++)
      af[mi] = *(const s16x8*)&As[cur][(wr * 64 + mi * 16 + l15) * 32 + lh * 8];
#pragma unroll
    for (int ni = 0; ni < 4; ni++)
      bf[ni] = *(const s16x8*)&Bs[cur][(wc * 64 + ni * 16 + l15) * 32 + lh * 8];
    __builtin_amdgcn_s_setprio(1);
#pragma unroll
    for (int mi = 0; mi < 4; mi++)
#pragma unroll
      for (int ni = 0; ni < 4; ni++)
        acc[mi][ni] = __builtin_amdgcn_mfma_f32_16x16x32_bf16(
            af[mi], bf[ni], acc[mi][ni], 0, 0, 0);
    __builtin_amdgcn_s_setprio(0);

    __builtin_amdgcn_s_barrier();        // all waves done reading cur
    __builtin_amdgcn_sched_barrier(0);
    cur ^= 1;
  }

  // epilogue: bias + scatter
  const int part = tn >> 10;  // 0=Q 1=K 2=V (uniform per block)
#pragma unroll
  for (int ni = 0; ni < 4; ni++) {
    const int n = tn + wc * 64 + ni * 16 + l15;
    const float bv = bias[n];
    const int n1 = n & 1023;
    const int h = n1 >> 6, d = n1 & 63;
#pragma unroll
    for (int mi = 0; mi < 4; mi++) {
#pragma unroll
      for (int r = 0; r < 4; r++) {
        const int m = tm + wr * 64 + mi * 16 + lh * 4 + r;
        const int b = m >> 11, t = m & 2047;
        float v = acc[mi][ni][r] + bv;
        if (part == 0) {
          v *= QSCALE;
          Q[((size_t)(b * NH + h) * NT + t) * DK + d] = f2bf(v);
        } else if (part == 1) {
          Kd[((size_t)(b * NH + h) * NT + t) * DK + d] = f2bf(v);
        } else {
          VT[((size_t)(b * NH + h) * DK + d) * NT + t] = f2bf(v);
        }
      }
    }
  }
}

// ---------------- Flash attention v13 (triple-buffer, 1 barrier/tile) --------
// r16 structure (8-wave/512-thread, shift-free softmax, counted vmcnt, MFMA
// rowsum, XCD swizzle, setprio) with K/V TRIPLE-buffered: iter j reads
// buf[j%3] and issues into buf[(j+1)%3]; buf[j%3] is next written at iter
// j+2's issue, and every wave passes barrier(j+1) in between -> the single
// top-of-loop barrier is sufficient (r16's end-barrier existed only because
// 2 buffers give zero barrier slack). 32 fewer barriers/block. LDS 64KB.
// Q,K: (BH,T,64) bf16 (Q pre-scaled); VT: (BH,64,T) bf16; out fp32 (B,T,H,64).
// K/V swizzle: 16B chunk c of row at c^(row&7) (pre-swizzled global source,
// linear LDS dest). Ps swizzle: chunk c at c^((row>>1)&3).
__global__ __launch_bounds__(512) void attn_kernel(
    const unsigned short* __restrict__ Q, const unsigned short* __restrict__ K,
    const unsigned short* __restrict__ VT, float* __restrict__ out) {
  __shared__ unsigned short Ks[3][64 * 64];   // [buf][key][d]  3x8KB
  __shared__ unsigned short Vs[3][64 * 64];   // [buf][d][key]  3x8KB
  __shared__ unsigned short Ps[8][32 * 32];   // per-wave P half 16KB

  const int tid = threadIdx.x, lane = tid & 63, wave = tid >> 6;
  const int l15 = lane & 15, lh = lane >> 4;
  const int orig = ((blockIdx.x & 7) << 6) + (blockIdx.x >> 3);
  const int bh = orig >> 3;         // 64 (b,h) pairs
  const int qt = orig & 7;          // 8 q-tiles of 256 rows
  const size_t base = (size_t)bh * NT * DK;
  const int qrow0 = qt * 256 + wave * 32;

  const int srow = tid >> 3, schunk = tid & 7;
  const int ssw = ((schunk ^ (srow & 7)) << 3);

  // Q fragments (MFMA B operand): Q[query=l15][d=lh*8..]
  s16x8 qf[2][2];
#pragma unroll
  for (int mi = 0; mi < 2; mi++)
#pragma unroll
    for (int kk = 0; kk < 2; kk++)
      qf[mi][kk] = *(const s16x8*)&Q[base + (size_t)(qrow0 + mi * 16 + l15) * DK +
                                     kk * 32 + lh * 8];

  f32x4 acc_o[2][4] = {};
  f32x4 acc_s[2] = {};   // rowsum accumulators (denominator)
  const s16x8 ones = {16256, 16256, 16256, 16256, 16256, 16256, 16256, 16256};

  // prologue: ISSUE K[0],V[0] into buf 0 (no wait; loop handles it)
  async_copy16(&Ks[0][(wave * 64) * 8], &K[base + (size_t)srow * DK + ssw]);
  async_copy16(&Vs[0][(wave * 64) * 8], &VT[base + (size_t)srow * NT + ssw]);

  int cur = 0;
  for (int j = 0; j < NT; j += 64) {
    int nxt = cur + 1; if (nxt == 3) nxt = 0;
    // issue NEXT tile's loads, then wait only for the TILE-OLD pair
    if (j + 64 < NT) {
      async_copy16(&Ks[nxt][(wave * 64) * 8],
                   &K[base + (size_t)(j + 64 + srow) * DK + ssw]);
      async_copy16(&Vs[nxt][(wave * 64) * 8],
                   &VT[base + (size_t)srow * NT + j + 64 + ssw]);
      asm volatile("s_waitcnt vmcnt(2)" ::: "memory");
    } else {
      asm volatile("s_waitcnt vmcnt(0)" ::: "memory");
    }
    __builtin_amdgcn_s_barrier();        // tile-j data visible to all waves
    __builtin_amdgcn_sched_barrier(0);

    // S^T = K @ Q^T : st[ki][mi] rows=keys(ki*16+lh*4+r), cols=queries(mi*16+l15)
    f32x4 st[4][2] = {};
    __builtin_amdgcn_s_setprio(1);
#pragma unroll
    for (int ki = 0; ki < 4; ki++) {
      const int row = ki * 16 + l15;
      const unsigned short* kr = &Ks[cur][row * 64];
      s16x8 kf0 = *(const s16x8*)&kr[((lh ^ (row & 7)) << 3)];
      s16x8 kf1 = *(const s16x8*)&kr[(((4 + lh) ^ (row & 7)) << 3)];
#pragma unroll
      for (int mi = 0; mi < 2; mi++) {
        st[ki][mi] = __builtin_amdgcn_mfma_f32_16x16x32_bf16(kf0, qf[mi][0], st[ki][mi], 0, 0, 0);
        st[ki][mi] = __builtin_amdgcn_mfma_f32_16x16x32_bf16(kf1, qf[mi][1], st[ki][mi], 0, 0, 0);
      }
    }
    __builtin_amdgcn_s_setprio(0);

    // shift-free softmax: p = exp2(s); pack bf16 pairs
    uint2 pw[2][4];   // [mi][ki]
#pragma unroll
    for (int mi = 0; mi < 2; mi++) {
#pragma unroll
      for (int ki = 0; ki < 4; ki++) {
        float p0 = exp2f(st[ki][mi][0]);
        float p1 = exp2f(st[ki][mi][1]);
        float p2 = exp2f(st[ki][mi][2]);
        float p3 = exp2f(st[ki][mi][3]);
        pw[mi][ki].x = cvt_pk_bf16(p0, p1);
        pw[mi][ki].y = cvt_pk_bf16(p2, p3);
      }
    }

    // PV + denominator: two kk-halves through the 2KB/wave Ps buffer
    // (per-wave DS ops are in-order -> no barrier needed for Ps reuse)
#pragma unroll
    for (int kk = 0; kk < 2; kk++) {
#pragma unroll
      for (int mi = 0; mi < 2; mi++) {
        const int row = mi * 16 + l15;
#pragma unroll
        for (int k2 = 0; k2 < 2; k2++) {
          const int cw = k2 * 2 + (lh >> 1);
          *(uint2*)&Ps[wave][row * 32 + ((cw ^ ((row >> 1) & 3)) << 3) +
                             (lh & 1) * 4] = pw[mi][kk * 2 + k2];
        }
      }
      const int r0 = l15, r1 = 16 + l15;
      s16x8 pa0 = *(const s16x8*)&Ps[wave][r0 * 32 + ((lh ^ ((r0 >> 1) & 3)) << 3)];
      s16x8 pa1 = *(const s16x8*)&Ps[wave][r1 * 32 + ((lh ^ ((r1 >> 1) & 3)) << 3)];
      __builtin_amdgcn_s_setprio(1);
      acc_s[0] = __builtin_amdgcn_mfma_f32_16x16x32_bf16(pa0, ones, acc_s[0], 0, 0, 0);
      acc_s[1] = __builtin_amdgcn_mfma_f32_16x16x32_bf16(pa1, ones, acc_s[1], 0, 0, 0);
#pragma unroll
      for (int nd = 0; nd < 4; nd++) {
        const int vrow = nd * 16 + l15;
        s16x8 vf = *(const s16x8*)&Vs[cur][vrow * 64 + (((kk * 4 + lh) ^ (vrow & 7)) << 3)];
        acc_o[0][nd] = __builtin_amdgcn_mfma_f32_16x16x32_bf16(pa0, vf, acc_o[0][nd], 0, 0, 0);
        acc_o[1][nd] = __builtin_amdgcn_mfma_f32_16x16x32_bf16(pa1, vf, acc_o[1][nd], 0, 0, 0);
      }
      __builtin_amdgcn_s_setprio(0);
    }

    cur = nxt;
  }

  // epilogue: lane-local normalize (acc_s[mi][r] aligns with acc_o[mi][nd][r])
  const int b = bh >> 4, h = bh & 15;
#pragma unroll
  for (int mi = 0; mi < 2; mi++)
#pragma unroll
    for (int r = 0; r < 4; r++) {
      const float rb = 1.0f / acc_s[mi][r];
      const int t = qrow0 + mi * 16 + lh * 4 + r;
#pragma unroll
      for (int nd = 0; nd < 4; nd++) {
        const int d = nd * 16 + l15;
        out[(((size_t)b * NT + t) * NH + h) * DK + d] = acc_o[mi][nd][r] * rb;
      }
    }
}

extern "C" void kernel_launch(void* const* d_in, const int* in_sizes, int n_in,
                              void* d_out, int out_size, void* d_ws, size_t ws_size,
                              hipStream_t stream) {
  const float* x = (const float*)d_in[0];
  const float* W = (const float*)d_in[1];
  const float* bias = (const float*)d_in[2];
  float* out = (float*)d_out;
  char* ws = (char*)d_ws;

  unsigned short* Xb = (unsigned short*)(ws);                       // 16.78 MB
  unsigned short* WT = (unsigned short*)(ws + 16777216);            // 6.29 MB
  unsigned short* Q  = (unsigned short*)(ws + 23068672);            // 16.78 MB
  unsigned short* Kd = (unsigned short*)(ws + 39845888);            // 16.78 MB
  unsigned short* VT = (unsigned short*)(ws + 56623104);            // 16.78 MB

  prep_kernel<<<8960, 256, 0, stream>>>(x, Xb, W, WT);
  qkv_gemm_kernel<<<1536, 256, 0, stream>>>(Xb, WT, bias, Q, Kd, VT);
  attn_kernel<<<512, 512, 0, stream>>>(Q, Kd, VT, out);
}

// Round 18
// 194.144 us; speedup vs baseline: 1.0771x; 1.0100x over previous
//
#include <hip/hip_runtime.h>
#include <hip/hip_bf16.h>

typedef float f32x4 __attribute__((ext_vector_type(4)));
typedef short s16x8 __attribute__((ext_vector_type(8)));

#define NB 4
#define NT 2048
#define NH 16
#define DK 64
#define DM 1024
#define MTOT (NB * NT)   // 8192
#define NTOT (3 * DM)    // 3072

// log2(e) / sqrt(64)
#define QSCALE 0.18033688011112042f

__device__ __forceinline__ unsigned short f2bf(float f) {
  union { float f; unsigned u; } v; v.f = f;
  unsigned r = v.u + 0x7fff + ((v.u >> 16) & 1);
  return (unsigned short)(r >> 16);
}

__device__ __forceinline__ unsigned cvt_pk_bf16(float a, float b) {
  unsigned r;
  asm("v_cvt_pk_bf16_f32 %0, %1, %2" : "=v"(r) : "v"(a), "v"(b));
  return r;
}

__device__ __forceinline__ void async_copy16(void* lds, const void* g) {
  __builtin_amdgcn_global_load_lds(
      (const __attribute__((address_space(1))) unsigned int*)g,
      (__attribute__((address_space(3))) unsigned int*)lds, 16, 0, 0);
}

// ---------------- fused prep: x -> bf16  AND  W -> WT bf16 -------------------
__global__ void prep_kernel(const float* __restrict__ x,
                            unsigned short* __restrict__ xb,
                            const float* __restrict__ W,
                            unsigned short* __restrict__ WT) {
  if (blockIdx.x < 8192) {
    int i = (blockIdx.x * 256 + threadIdx.x) * 4;
    float4 v = *reinterpret_cast<const float4*>(x + i);
    ushort4 o;
    o.x = f2bf(v.x); o.y = f2bf(v.y); o.z = f2bf(v.z); o.w = f2bf(v.w);
    *reinterpret_cast<ushort4*>(xb + i) = o;
  } else {
    __shared__ float tile[64][65];
    const int bb = blockIdx.x - 8192;
    const int n0 = (bb % 48) * 64;   // over 3072
    const int k0 = (bb / 48) * 64;   // over 1024
    const int t = threadIdx.x;       // 256
    const int col = t & 63;
    const int rw = t >> 6;
#pragma unroll
    for (int r = 0; r < 16; r++) {
      int row = r * 4 + rw;          // k offset
      tile[row][col] = W[(size_t)(k0 + row) * NTOT + n0 + col];
    }
    __syncthreads();
#pragma unroll
    for (int r = 0; r < 16; r++) {
      int row = r * 4 + rw;          // n offset
      WT[(size_t)(n0 + row) * DM + k0 + col] = f2bf(tile[col][row]);
    }
  }
}

// ---------------- QKV GEMM (depth-2 pipeline, 3 buffers, 1 barrier/step) -----
// Tile k's loads are issued at step k-2 (~2 K-steps of compute = 200+ cyc)
// -> L2 latency covered. Per step: vmcnt(4) waits only tile-k's loads
// (tile k+1 stays in flight); single raw barrier; THEN issue tile k+2 into
// buf[(k+2)%3] (post-barrier => all waves are done reading that buffer,
// last touched at step k-1). No second barrier needed (3-buffer slack).
__global__ __launch_bounds__(256) void qkv_gemm_kernel(
    const unsigned short* __restrict__ A, const unsigned short* __restrict__ BT,
    const float* __restrict__ bias, unsigned short* __restrict__ Q,
    unsigned short* __restrict__ Kd, unsigned short* __restrict__ VT) {
  __shared__ unsigned short As[3][128 * 32];
  __shared__ unsigned short Bs[3][128 * 32];
  const int tid = threadIdx.x;
  const int lane = tid & 63;
  const int wave = tid >> 6;
  const int wr = wave >> 1, wc = wave & 1;
  const int l15 = lane & 15, lh = lane >> 4;

  const int orig = ((blockIdx.x & 7) * 192) + (blockIdx.x >> 3);
  const int nTilesN = NTOT / 128;  // 24
  const int tm = (orig / nTilesN) * 128;
  const int tn = (orig % nTilesN) * 128;

  const int srow = (tid >> 2), scol = (tid & 3) << 3;
  const int srow2 = ((256 + tid) >> 2), scol2 = ((256 + tid) & 3) << 3;

  f32x4 acc[4][4] = {};

  // prologue: issue tiles 0 and 1
  async_copy16(&As[0][(wave * 64) * 8], &A[(size_t)(tm + srow) * DM + scol]);
  async_copy16(&Bs[0][(wave * 64) * 8], &BT[(size_t)(tn + srow) * DM + scol]);
  async_copy16(&As[0][(256 + wave * 64) * 8], &A[(size_t)(tm + srow2) * DM + scol2]);
  async_copy16(&Bs[0][(256 + wave * 64) * 8], &BT[(size_t)(tn + srow2) * DM + scol2]);
  async_copy16(&As[1][(wave * 64) * 8], &A[(size_t)(tm + srow) * DM + 32 + scol]);
  async_copy16(&Bs[1][(wave * 64) * 8], &BT[(size_t)(tn + srow) * DM + 32 + scol]);
  async_copy16(&As[1][(256 + wave * 64) * 8], &A[(size_t)(tm + srow2) * DM + 32 + scol2]);
  async_copy16(&Bs[1][(256 + wave * 64) * 8], &BT[(size_t)(tn + srow2) * DM + 32 + scol2]);

  int cur = 0;
  for (int step = 0; step < 32; step++) {
    // wait: tile-step's 4 loads landed (tile step+1's 4 may remain in flight)
    if (step <= 30) {
      asm volatile("s_waitcnt vmcnt(4)" ::: "memory");
    } else {
      asm volatile("s_waitcnt vmcnt(0)" ::: "memory");
    }
    __builtin_amdgcn_s_barrier();        // tile data visible; prior reads done
    __builtin_amdgcn_sched_barrier(0);

    // issue tile step+2 into buf[(step+2)%3] (safe: post-barrier)
    if (step + 2 < 32) {
      int nb = cur + 2; if (nb >= 3) nb -= 3;
      const int kn = (step + 2) * 32;
      async_copy16(&As[nb][(wave * 64) * 8], &A[(size_t)(tm + srow) * DM + kn + scol]);
      async_copy16(&Bs[nb][(wave * 64) * 8], &BT[(size_t)(tn + srow) * DM + kn + scol]);
      async_copy16(&As[nb][(256 + wave * 64) * 8], &A[(size_t)(tm + srow2) * DM + kn + scol2]);
      async_copy16(&Bs[nb][(256 + wave * 64) * 8], &BT[(size_t)(tn + srow2) * DM + kn + scol2]);
    }

    s16x8 af[4], bf[4];
#pragma unroll
    for (int mi = 0; mi < 4; mi++)
      af[mi] = *(const s16x8*)&As[cur][(wr * 64 + mi * 16 + l15) * 32 + lh * 8];
#pragma unroll
    for (int ni = 0; ni < 4; ni++)
      bf[ni] = *(const s16x8*)&Bs[cur][(wc * 64 + ni * 16 + l15) * 32 + lh * 8];
    __builtin_amdgcn_s_setprio(1);
#pragma unroll
    for (int mi = 0; mi < 4; mi++)
#pragma unroll
      for (int ni = 0; ni < 4; ni++)
        acc[mi][ni] = __builtin_amdgcn_mfma_f32_16x16x32_bf16(
            af[mi], bf[ni], acc[mi][ni], 0, 0, 0);
    __builtin_amdgcn_s_setprio(0);

    cur = cur + 1; if (cur == 3) cur = 0;
  }

  // epilogue: bias + scatter
  const int part = tn >> 10;  // 0=Q 1=K 2=V (uniform per block)
#pragma unroll
  for (int ni = 0; ni < 4; ni++) {
    const int n = tn + wc * 64 + ni * 16 + l15;
    const float bv = bias[n];
    const int n1 = n & 1023;
    const int h = n1 >> 6, d = n1 & 63;
#pragma unroll
    for (int mi = 0; mi < 4; mi++) {
#pragma unroll
      for (int r = 0; r < 4; r++) {
        const int m = tm + wr * 64 + mi * 16 + lh * 4 + r;
        const int b = m >> 11, t = m & 2047;
        float v = acc[mi][ni][r] + bv;
        if (part == 0) {
          v *= QSCALE;
          Q[((size_t)(b * NH + h) * NT + t) * DK + d] = f2bf(v);
        } else if (part == 1) {
          Kd[((size_t)(b * NH + h) * NT + t) * DK + d] = f2bf(v);
        } else {
          VT[((size_t)(b * NH + h) * DK + d) * NT + t] = f2bf(v);
        }
      }
    }
  }
}

// ---------------- Flash attention v13 (r17 exact: best known, 111.4us) -------
// 8-wave/512-thread, shift-free softmax, K/V triple-buffered, 1 barrier/tile,
// counted vmcnt, MFMA rowsum, XCD swizzle, setprio.
__global__ __launch_bounds__(512) void attn_kernel(
    const unsigned short* __restrict__ Q, const unsigned short* __restrict__ K,
    const unsigned short* __restrict__ VT, float* __restrict__ out) {
  __shared__ unsigned short Ks[3][64 * 64];   // [buf][key][d]  3x8KB
  __shared__ unsigned short Vs[3][64 * 64];   // [buf][d][key]  3x8KB
  __shared__ unsigned short Ps[8][32 * 32];   // per-wave P half 16KB

  const int tid = threadIdx.x, lane = tid & 63, wave = tid >> 6;
  const int l15 = lane & 15, lh = lane >> 4;
  const int orig = ((blockIdx.x & 7) << 6) + (blockIdx.x >> 3);
  const int bh = orig >> 3;         // 64 (b,h) pairs
  const int qt = orig & 7;          // 8 q-tiles of 256 rows
  const size_t base = (size_t)bh * NT * DK;
  const int qrow0 = qt * 256 + wave * 32;

  const int srow = tid >> 3, schunk = tid & 7;
  const int ssw = ((schunk ^ (srow & 7)) << 3);

  // Q fragments (MFMA B operand): Q[query=l15][d=lh*8..]
  s16x8 qf[2][2];
#pragma unroll
  for (int mi = 0; mi < 2; mi++)
#pragma unroll
    for (int kk = 0; kk < 2; kk++)
      qf[mi][kk] = *(const s16x8*)&Q[base + (size_t)(qrow0 + mi * 16 + l15) * DK +
                                     kk * 32 + lh * 8];

  f32x4 acc_o[2][4] = {};
  f32x4 acc_s[2] = {};   // rowsum accumulators (denominator)
  const s16x8 ones = {16256, 16256, 16256, 16256, 16256, 16256, 16256, 16256};

  // prologue: ISSUE K[0],V[0] into buf 0 (no wait; loop handles it)
  async_copy16(&Ks[0][(wave * 64) * 8], &K[base + (size_t)srow * DK + ssw]);
  async_copy16(&Vs[0][(wave * 64) * 8], &VT[base + (size_t)srow * NT + ssw]);

  int cur = 0;
  for (int j = 0; j < NT; j += 64) {
    int nxt = cur + 1; if (nxt == 3) nxt = 0;
    // issue NEXT tile's loads, then wait only for the TILE-OLD pair
    if (j + 64 < NT) {
      async_copy16(&Ks[nxt][(wave * 64) * 8],
                   &K[base + (size_t)(j + 64 + srow) * DK + ssw]);
      async_copy16(&Vs[nxt][(wave * 64) * 8],
                   &VT[base + (size_t)srow * NT + j + 64 + ssw]);
      asm volatile("s_waitcnt vmcnt(2)" ::: "memory");
    } else {
      asm volatile("s_waitcnt vmcnt(0)" ::: "memory");
    }
    __builtin_amdgcn_s_barrier();        // tile-j data visible to all waves
    __builtin_amdgcn_sched_barrier(0);

    // S^T = K @ Q^T : st[ki][mi] rows=keys(ki*16+lh*4+r), cols=queries(mi*16+l15)
    f32x4 st[4][2] = {};
    __builtin_amdgcn_s_setprio(1);
#pragma unroll
    for (int ki = 0; ki < 4; ki++) {
      const int row = ki * 16 + l15;
      const unsigned short* kr = &Ks[cur][row * 64];
      s16x8 kf0 = *(const s16x8*)&kr[((lh ^ (row & 7)) << 3)];
      s16x8 kf1 = *(const s16x8*)&kr[(((4 + lh) ^ (row & 7)) << 3)];
#pragma unroll
      for (int mi = 0; mi < 2; mi++) {
        st[ki][mi] = __builtin_amdgcn_mfma_f32_16x16x32_bf16(kf0, qf[mi][0], st[ki][mi], 0, 0, 0);
        st[ki][mi] = __builtin_amdgcn_mfma_f32_16x16x32_bf16(kf1, qf[mi][1], st[ki][mi], 0, 0, 0);
      }
    }
    __builtin_amdgcn_s_setprio(0);

    // shift-free softmax: p = exp2(s); pack bf16 pairs
    uint2 pw[2][4];   // [mi][ki]
#pragma unroll
    for (int mi = 0; mi < 2; mi++) {
#pragma unroll
      for (int ki = 0; ki < 4; ki++) {
        float p0 = exp2f(st[ki][mi][0]);
        float p1 = exp2f(st[ki][mi][1]);
        float p2 = exp2f(st[ki][mi][2]);
        float p3 = exp2f(st[ki][mi][3]);
        pw[mi][ki].x = cvt_pk_bf16(p0, p1);
        pw[mi][ki].y = cvt_pk_bf16(p2, p3);
      }
    }

    // PV + denominator: two kk-halves through the 2KB/wave Ps buffer
#pragma unroll
    for (int kk = 0; kk < 2; kk++) {
#pragma unroll
      for (int mi = 0; mi < 2; mi++) {
        const int row = mi * 16 + l15;
#pragma unroll
        for (int k2 = 0; k2 < 2; k2++) {
          const int cw = k2 * 2 + (lh >> 1);
          *(uint2*)&Ps[wave][row * 32 + ((cw ^ ((row >> 1) & 3)) << 3) +
                             (lh & 1) * 4] = pw[mi][kk * 2 + k2];
        }
      }
      const int r0 = l15, r1 = 16 + l15;
      s16x8 pa0 = *(const s16x8*)&Ps[wave][r0 * 32 + ((lh ^ ((r0 >> 1) & 3)) << 3)];
      s16x8 pa1 = *(const s16x8*)&Ps[wave][r1 * 32 + ((lh ^ ((r1 >> 1) & 3)) << 3)];
      __builtin_amdgcn_s_setprio(1);
      acc_s[0] = __builtin_amdgcn_mfma_f32_16x16x32_bf16(pa0, ones, acc_s[0], 0, 0, 0);
      acc_s[1] = __builtin_amdgcn_mfma_f32_16x16x32_bf16(pa1, ones, acc_s[1], 0, 0, 0);
#pragma unroll
      for (int nd = 0; nd < 4; nd++) {
        const int vrow = nd * 16 + l15;
        s16x8 vf = *(const s16x8*)&Vs[cur][vrow * 64 + (((kk * 4 + lh) ^ (vrow & 7)) << 3)];
        acc_o[0][nd] = __builtin_amdgcn_mfma_f32_16x16x32_bf16(pa0, vf, acc_o[0][nd], 0, 0, 0);
        acc_o[1][nd] = __builtin_amdgcn_mfma_f32_16x16x32_bf16(pa1, vf, acc_o[1][nd], 0, 0, 0);
      }
      __builtin_amdgcn_s_setprio(0);
    }

    cur = nxt;
  }

  // epilogue: lane-local normalize (acc_s[mi][r] aligns with acc_o[mi][nd][r])
  const int b = bh >> 4, h = bh & 15;
#pragma unroll
  for (int mi = 0; mi < 2; mi++)
#pragma unroll
    for (int r = 0; r < 4; r++) {
      const float rb = 1.0f / acc_s[mi][r];
      const int t = qrow0 + mi * 16 + lh * 4 + r;
#pragma unroll
      for (int nd = 0; nd < 4; nd++) {
        const int d = nd * 16 + l15;
        out[(((size_t)b * NT + t) * NH + h) * DK + d] = acc_o[mi][nd][r] * rb;
      }
    }
}

extern "C" void kernel_launch(void* const* d_in, const int* in_sizes, int n_in,
                              void* d_out, int out_size, void* d_ws, size_t ws_size,
                              hipStream_t stream) {
  const float* x = (const float*)d_in[0];
  const float* W = (const float*)d_in[1];
  const float* bias = (const float*)d_in[2];
  float* out = (float*)d_out;
  char* ws = (char*)d_ws;

  unsigned short* Xb = (unsigned short*)(ws);                       // 16.78 MB
  unsigned short* WT = (unsigned short*)(ws + 16777216);            // 6.29 MB
  unsigned short* Q  = (unsigned short*)(ws + 23068672);            // 16.78 MB
  unsigned short* Kd = (unsigned short*)(ws + 39845888);            // 16.78 MB
  unsigned short* VT = (unsigned short*)(ws + 56623104);            // 16.78 MB

  prep_kernel<<<8960, 256, 0, stream>>>(x, Xb, W, WT);
  qkv_gemm_kernel<<<1536, 256, 0, stream>>>(Xb, WT, bias, Q, Kd, VT);
  attn_kernel<<<512, 512, 0, stream>>>(Q, Kd, VT, out);
}